// Round 6
// baseline (734.188 us; speedup 1.0000x reference)
//
#include <hip/hip_runtime.h>
#include <math.h>

// ---------------------------------------------------------------------------
// Round 6: k3 convs moved to 32x32x16 MFMA (2x fewer operand bytes/MAC than
// 16x16x32 -- R5 was LDS-read + weight-L2 bound at MfmaUtil 23%). 16-cin
// k-group slicing (LDS pixel = 40 f16) -> hx0 uses 256-px tile at 51.8KB LDS
// (3 blocks/CU). Same 3xf16 split-precision emulation (verified absmax
// 0.0078 vs 0.052). conv_k2 kernels unchanged from R5.
// ---------------------------------------------------------------------------

typedef _Float16 f16;
typedef _Float16 f16x8 __attribute__((ext_vector_type(8)));
typedef _Float16 f16x4 __attribute__((ext_vector_type(4)));
typedef float    f32x4 __attribute__((ext_vector_type(4)));
typedef float    f32x16 __attribute__((ext_vector_type(16)));

#define PIX  72   // k2 LDS pixel: 64 payload + 8 pad (f16)
#define PIX2 40   // k3-32 LDS pixel: 32 payload (hi0 hi1 lo0 lo1) + 8 pad

// ---- weight packing ----
// 16x16x32 A-layout (conv_k2): cout = gmt*16+(l&15), cin = h*32+((l>>4)&3)*8+j
__device__ inline void pack_one16(const float* __restrict__ w, f16* __restrict__ wp,
                                  int Cin, int taps, int CH, int NMT, int e, int lane)
{
    const int gmt = e % NMT;
    const int sel = (e / NMT) % 2;
    const int h   = (e / (NMT * 2)) % CH;
    const int tap = e / (NMT * 2 * CH);
    const int cout = gmt * 16 + (lane & 15);
    const int cin0 = h * 32 + ((lane >> 4) & 3) * 8;
    f16x8 v;
    for (int j = 0; j < 8; ++j) {
        float x = w[((size_t)cout * Cin + cin0 + j) * taps + tap];
        f16 hi = (f16)x;
        v[j] = sel ? (f16)(x - (float)hi) : hi;
    }
    *(f16x8*)&wp[((size_t)e * 64 + lane) * 8] = v;
}

// 32x32x16 A-layout (conv_k3): cout = mt*32+(l&31), cin = g*16+(l>>5)*8+j
__device__ inline void pack_one32(const float* __restrict__ w, f16* __restrict__ wp,
                                  int Cin, int taps, int NMT, int e, int lane)
{
    const int mt  = e % NMT;
    const int sel = (e / NMT) % 2;
    const int g   = (e / (NMT * 2)) % 4;
    const int tap = e / (NMT * 2 * 4);
    const int cout = mt * 32 + (lane & 31);
    const int cin0 = g * 16 + (lane >> 5) * 8;
    f16x8 v;
    for (int j = 0; j < 8; ++j) {
        float x = w[((size_t)cout * Cin + cin0 + j) * taps + tap];
        f16 hi = (f16)x;
        v[j] = sel ? (f16)(x - (float)hi) : hi;
    }
    *(f16x8*)&wp[((size_t)e * 64 + lane) * 8] = v;
}

__global__ void pack_all(
    const float* wh, const float* wc0, const float* wr0,
    const float* wr1, const float* wc1, const float* wout,
    f16* ph, f16* pc0, f16* pr0, f16* pr1, f16* pc1, f16* pout)
{
    const int b = blockIdx.x, lane = threadIdx.x;
    if      (b < 64)   pack_one16(wh,   ph,   32, 8,  1, 4, b,        lane);
    else if (b < 192)  pack_one16(wc0,  pc0,  64, 8,  2, 4, b - 64,   lane);
    else if (b < 624)  pack_one32(wr0,  pr0,  64, 27, 2,    b - 192,  lane);
    else if (b < 1056) pack_one32(wr1,  pr1,  64, 27, 2,    b - 624,  lane);
    else if (b < 1488) pack_one32(wc1,  pc1,  64, 27, 2,    b - 1056, lane);
    else               pack_one32(wout, pout, 64, 27, 1,    b - 1488, lane);
}

// Octant swizzle for XCD L2 locality.
template<int NXC, int NYC, int NZC>
__device__ inline void tile_coords(int bid, int& xc, int& yb, int& zb)
{
    if ((NXC % 2 == 0) && (NYC % 2 == 0) && (NZC % 2 == 0) && (NXC*NYC*NZC >= 64)) {
        const int o = bid & 7, j = bid >> 3;
        constexpr int HX = NXC / 2, HY = NYC / 2;
        xc = (j % HX) + (o & 1) * HX;
        yb = ((j / HX) % HY) + ((o >> 1) & 1) * HY;
        zb = (j / (HX * HY)) + (o >> 2) * (NZC / 2);
    } else {
        xc = bid % NXC;
        yb = (bid / NXC) % NYC;
        zb = bid / (NXC * NYC);
    }
}

// ---------------- k3 s1 SAME conv, Cin=64, 32x32x16 MFMA ----------------
// 4 waves = NG ngroups x (4/NG) mgroups, MTW=1 (NMT = 4/NG m-tiles of 32).
// Block px = NG*NT*32 = TX*TY*TZ. K sliced into 4 groups of 16 cins; per
// group the LDS pixel holds [hi0|hi1|lo0|lo1] 8-f16 chunks (PIX2=40).
// A-frag: m=lane&31, k=(lane>>5)*8+j. B-frag: n(px)=lane&31, same k split.
// C/D: col(px)=lane&31, row=(r&3)+8*(r>>2)+4*(lane>>5).
template<int S, int TX, int TY, int TZ, int NG, int NT, int ACT_C, bool SRCF32>
__global__ __launch_bounds__(256) void conv_k3(
    const void* __restrict__ in_, const f16* __restrict__ wp,
    const f16* __restrict__ addsrc, f16* __restrict__ act_out,
    float* __restrict__ f32_out, int relu, float scale)
{
    constexpr int S2 = S * S, S3 = S2 * S;
    constexpr int XP = TX + 2, YP = TY + 2, ZP = TZ + 2;
    constexpr int NPX = XP * YP * ZP;
    constexpr int NXC = S / TX, NYC = S / TY, NZC = S / TZ;
    constexpr int NMT = 4 / NG;
    static_assert(TX * TY * TZ == NG * NT * 32, "tile/wave mismatch");
    __shared__ __align__(16) f16 sm[NPX * PIX2];

    int xc, yb, zb;
    tile_coords<NXC, NYC, NZC>(blockIdx.x, xc, yb, zb);
    const int x0 = xc * TX, y0 = yb * TY, z0 = zb * TZ;

    const int tid  = threadIdx.x;
    const int lane = tid & 63;
    const int wave = tid >> 6;
    const int l31  = lane & 31;
    const int half = lane >> 5;
    const int ng = wave % NG, mg = wave / NG;

    int lx[NT], ly[NT], lz[NT];
#pragma unroll
    for (int t = 0; t < NT; ++t) {
        const int p = (ng * NT + t) * 32 + l31;
        lx[t] = p % TX; ly[t] = (p / TX) % TY; lz[t] = p / (TX * TY);
    }

    f32x16 acc[NT];
#pragma unroll
    for (int t = 0; t < NT; ++t)
#pragma unroll
        for (int r = 0; r < 16; ++r) acc[t][r] = 0.f;

    for (int g = 0; g < 4; ++g) {
        __syncthreads();
        if (SRCF32) {
            // one iteration: 8 f32 loads -> hi chunk + lo chunk
            const float* src = (const float*)in_;
            for (int it = tid; it < NPX * 2; it += 256) {
                const int cp = it & 1;
                const int pxl = it >> 1;
                const int xp = pxl % XP;
                const int row = pxl / XP;
                const int zr = row / YP, yr = row % YP;
                const int pz = z0 + zr - 1, py = y0 + yr - 1, px = x0 + xp - 1;
                const bool ok = (unsigned)pz < (unsigned)S && (unsigned)py < (unsigned)S
                             && (unsigned)px < (unsigned)S;
                f16x8 vh, vl;
                if (ok) {
                    const size_t pos = (size_t)(pz * S2 + py * S + px);
                    const int cbase = g * 16 + cp * 8;
#pragma unroll
                    for (int j = 0; j < 8; ++j) {
                        float x = src[(size_t)(cbase + j) * S3 + pos];
                        f16 hi = (f16)x;
                        vh[j] = hi;
                        vl[j] = (f16)(x - (float)hi);
                    }
                } else {
#pragma unroll
                    for (int j = 0; j < 8; ++j) { vh[j] = (f16)0.f; vl[j] = (f16)0.f; }
                }
                *(f16x8*)&sm[pxl * PIX2 + cp * 8] = vh;
                *(f16x8*)&sm[pxl * PIX2 + 16 + cp * 8] = vl;
            }
        } else {
            // f16 source [pos][hi c0..c7 | lo c0..c7]; group g = chunks 2g,2g+1
            const f16* src = (const f16*)in_;
            for (int it = tid; it < NPX * 4; it += 256) {
                const int cp = it & 1;
                const int sel = (it >> 1) & 1;
                const int pxl = it >> 2;
                const int xp = pxl % XP;
                const int row = pxl / XP;
                const int zr = row / YP, yr = row % YP;
                const int pz = z0 + zr - 1, py = y0 + yr - 1, px = x0 + xp - 1;
                const bool ok = (unsigned)pz < (unsigned)S && (unsigned)py < (unsigned)S
                             && (unsigned)px < (unsigned)S;
                f16x8 v;
                if (ok) {
                    const size_t pos = (size_t)(pz * S2 + py * S + px);
                    v = *(const f16x8*)&src[pos * 128 + sel * 64 + (2 * g + cp) * 8];
                } else {
#pragma unroll
                    for (int j = 0; j < 8; ++j) v[j] = (f16)0.f;
                }
                *(f16x8*)&sm[pxl * PIX2 + sel * 16 + cp * 8] = v;
            }
        }
        __syncthreads();

        for (int dz = 0; dz < 3; ++dz) {
#pragma unroll
            for (int dy = 0; dy < 3; ++dy) {
#pragma unroll
                for (int dx = 0; dx < 3; ++dx) {
                    const int tap = dz * 9 + dy * 3 + dx;
                    const f16x8 awh = *(const f16x8*)&wp[((size_t)((tap * 4 + g) * 2 + 0) * NMT + mg) * 512 + lane * 8];
                    const f16x8 awl = *(const f16x8*)&wp[((size_t)((tap * 4 + g) * 2 + 1) * NMT + mg) * 512 + lane * 8];
#pragma unroll
                    for (int t = 0; t < NT; ++t) {
                        const int pix = ((lz[t] + dz) * YP + ly[t] + dy) * XP + lx[t] + dx;
                        const f16x8 bh = *(const f16x8*)&sm[pix * PIX2 + half * 8];
                        const f16x8 bl = *(const f16x8*)&sm[pix * PIX2 + 16 + half * 8];
                        acc[t] = __builtin_amdgcn_mfma_f32_32x32x16_f16(awh, bh, acc[t], 0, 0, 0);
                        acc[t] = __builtin_amdgcn_mfma_f32_32x32x16_f16(awh, bl, acc[t], 0, 0, 0);
                        acc[t] = __builtin_amdgcn_mfma_f32_32x32x16_f16(awl, bh, acc[t], 0, 0, 0);
                    }
                }
            }
        }
    }

    // epilogue: col(px)=lane&31; rows m0..m0+3 per q, m0 = mg*32+8q+4*half
#pragma unroll
    for (int t = 0; t < NT; ++t) {
        const int pg = (z0 + lz[t]) * S2 + (y0 + ly[t]) * S + x0 + lx[t];
#pragma unroll
        for (int q = 0; q < 4; ++q) {
            const int m0 = mg * 32 + 8 * q + 4 * half;
            float a[4];
#pragma unroll
            for (int r = 0; r < 4; ++r) a[r] = acc[t][4 * q + r];
            if (addsrc) {
                const f16x4 ah = *(const f16x4*)&addsrc[(size_t)pg * 128 + m0];
                const f16x4 al = *(const f16x4*)&addsrc[(size_t)pg * 128 + 64 + m0];
#pragma unroll
                for (int r = 0; r < 4; ++r) a[r] += (float)ah[r] + (float)al[r];
            }
            if (relu) {
#pragma unroll
                for (int r = 0; r < 4; ++r) a[r] = fmaxf(a[r], 0.f);
            }
            if (act_out) {
                f16x4 hi, lo;
#pragma unroll
                for (int r = 0; r < 4; ++r) {
                    hi[r] = (f16)a[r];
                    lo[r] = (f16)(a[r] - (float)hi[r]);
                }
                *(f16x4*)&act_out[(size_t)pg * (2 * ACT_C) + m0] = hi;
                *(f16x4*)&act_out[(size_t)pg * (2 * ACT_C) + ACT_C + m0] = lo;
            }
            if (f32_out) {
#pragma unroll
                for (int r = 0; r < 4; ++r)
                    f32_out[(size_t)(m0 + r) * S3 + pg] = a[r] * scale;
            }
        }
    }
}

// ---------------- k2 s2 VALID conv (unchanged from R5, 16x16x32) ----------
template<int So, int TX, int TY, int TZ, int NMT, int CH, bool SRCF32, int SRC_C, bool GATE>
__global__ __launch_bounds__(256) void conv_k2(
    const void* __restrict__ in_, const f16* __restrict__ wp,
    f16* __restrict__ act_out, f16* __restrict__ cx, float src_scale)
{
    constexpr int So2 = So * So;
    constexpr int Si = 2 * So, Si2 = Si * Si, Si3 = Si2 * Si;
    constexpr int XI = 2 * TX, YI = 2 * TY, ZI = 2 * TZ;
    constexpr int NPX = XI * YI * ZI;
    constexpr int NXC = So / TX, NYC = So / TY, NZC = So / TZ;
    constexpr int MTW = NMT / 2;
    static_assert(TX * TY * TZ == 32, "k2 tile must be 32 px");
    __shared__ __align__(16) f16 sm[NPX * PIX];

    int xc, yb, zb;
    tile_coords<NXC, NYC, NZC>(blockIdx.x, xc, yb, zb);
    const int x0 = xc * TX, y0 = yb * TY, z0 = zb * TZ;

    const int tid  = threadIdx.x;
    const int lane = tid & 63;
    const int wave = tid >> 6;
    const int i15  = lane & 15, quad = (lane >> 4) & 3;
    const int nt = wave & 1, mh = wave >> 1;
    const int p = nt * 16 + i15;
    const int lx = p % TX, ly = (p / TX) % TY, lz = p / (TX * TY);

    f32x4 acc[MTW];
#pragma unroll
    for (int m = 0; m < MTW; ++m) { f32x4 z = {0.f,0.f,0.f,0.f}; acc[m] = z; }

    for (int h = 0; h < CH; ++h) {
        __syncthreads();
        if (SRCF32) {
            const float* src = (const float*)in_;
            for (int it = tid; it < NPX * 8; it += 256) {
                const int xp = it % XI;
                const int rem = it / XI;
                const int row = rem % (YI * ZI);
                const int cc = rem / (YI * ZI);
                const int zr = row / YI, yr = row % YI;
                const size_t pos = (size_t)((z0 * 2 + zr) * Si2 + (y0 * 2 + yr) * Si + x0 * 2 + xp);
                const int cbase = h * 32 + (cc & 3) * 8;
                f16x8 v;
#pragma unroll
                for (int j = 0; j < 8; ++j) {
                    float x = src[(size_t)(cbase + j) * Si3 + pos] * src_scale;
                    f16 hi = (f16)x;
                    v[j] = (cc < 4) ? hi : (f16)(x - (float)hi);
                }
                const int slot = (xp >> 1) + (xp & 1) * TX;
                *(f16x8*)&sm[(row * XI + slot) * PIX + (cc & 3) * 8 + (cc >> 2) * 32] = v;
            }
        } else {
            const f16* src = (const f16*)in_;
            for (int it = tid; it < NPX * 8; it += 256) {
                const int cc = it & 7;
                const int pxl = it >> 3;
                const int xp = pxl % XI;
                const int row = pxl / XI;
                const int zr = row / YI, yr = row % YI;
                const size_t pos = (size_t)((z0 * 2 + zr) * Si2 + (y0 * 2 + yr) * Si + x0 * 2 + xp);
                f16x8 v = *(const f16x8*)&src[pos * (2 * SRC_C) + (cc >> 2) * SRC_C + h * 32 + (cc & 3) * 8];
                const int slot = (xp >> 1) + (xp & 1) * TX;
                *(f16x8*)&sm[(row * XI + slot) * PIX + (cc & 3) * 8 + (cc >> 2) * 32] = v;
            }
        }
        __syncthreads();

#pragma unroll
        for (int dz = 0; dz < 2; ++dz) {
#pragma unroll
            for (int dy = 0; dy < 2; ++dy) {
#pragma unroll
                for (int dx = 0; dx < 2; ++dx) {
                    const int tap = dz * 4 + dy * 2 + dx;
                    const int pix = ((2 * lz + dz) * YI + 2 * ly + dy) * XI + lx + dx * TX;
                    const f16x8 bh = *(const f16x8*)&sm[pix * PIX + quad * 8];
                    const f16x8 bl = *(const f16x8*)&sm[pix * PIX + 32 + quad * 8];
#pragma unroll
                    for (int m = 0; m < MTW; ++m) {
                        const int gm = mh * MTW + m;
                        const f16x8 awh = *(const f16x8*)&wp[((size_t)((tap * CH + h) * 2 + 0) * NMT + gm) * 512 + lane * 8];
                        const f16x8 awl = *(const f16x8*)&wp[((size_t)((tap * CH + h) * 2 + 1) * NMT + gm) * 512 + lane * 8];
                        acc[m] = __builtin_amdgcn_mfma_f32_16x16x32_f16(awh, bh, acc[m], 0, 0, 0);
                        acc[m] = __builtin_amdgcn_mfma_f32_16x16x32_f16(awh, bl, acc[m], 0, 0, 0);
                        acc[m] = __builtin_amdgcn_mfma_f32_16x16x32_f16(awl, bh, acc[m], 0, 0, 0);
                    }
                }
            }
        }
    }

    const int pg = (z0 + lz) * So2 + (y0 + ly) * So + x0 + lx;
#pragma unroll
    for (int m = 0; m < MTW; ++m) {
        const int gm = mh * MTW + m;
        if (GATE) {
            f16x4 chi = *(const f16x4*)&cx[(size_t)pg * 128 + gm * 16 + quad * 4];
            f16x4 clo = *(const f16x4*)&cx[(size_t)pg * 128 + 64 + gm * 16 + quad * 4];
            f16x4 nhi, nlo;
#pragma unroll
            for (int r = 0; r < 4; ++r) {
                const float g = 1.0f / (1.0f + expf(-fmaxf(acc[m][r], 0.f)));
                float v = ((float)chi[r] + (float)clo[r]) * g;
                f16 hi = (f16)v;
                nhi[r] = hi;
                nlo[r] = (f16)(v - (float)hi);
            }
            *(f16x4*)&cx[(size_t)pg * 128 + gm * 16 + quad * 4] = nhi;
            *(f16x4*)&cx[(size_t)pg * 128 + 64 + gm * 16 + quad * 4] = nlo;
        } else {
            f16x4 hi, lo;
#pragma unroll
            for (int r = 0; r < 4; ++r) {
                const float a = fmaxf(acc[m][r], 0.f);
                hi[r] = (f16)a;
                lo[r] = (f16)(a - (float)hi[r]);
            }
            *(f16x4*)&act_out[(size_t)pg * 128 + gm * 16 + quad * 4] = hi;
            *(f16x4*)&act_out[(size_t)pg * 128 + 64 + gm * 16 + quad * 4] = lo;
        }
    }
}

extern "C" void kernel_launch(void* const* d_in, const int* in_sizes, int n_in,
                              void* d_out, int out_size, void* d_ws, size_t ws_size,
                              hipStream_t stream)
{
    const float* x     = (const float*)d_in[0];
    const float* w_h   = (const float*)d_in[1];
    const float* w_c0  = (const float*)d_in[2];
    const float* w_r0  = (const float*)d_in[3];
    const float* w_r1  = (const float*)d_in[4];
    const float* w_c1  = (const float*)d_in[5];
    const float* w_out = (const float*)d_in[6];
    float* out = (float*)d_out;
    f16* ws = (f16*)d_ws;

    // ws layout (f16 units) -- same sizes as R5 (~33 MB total)
    size_t o = 0;
    f16* wp_h   = ws + o; o += (size_t)64   * 512;
    f16* wp_c0  = ws + o; o += (size_t)128  * 512;
    f16* wp_r0  = ws + o; o += (size_t)432  * 512;
    f16* wp_r1  = ws + o; o += (size_t)432  * 512;
    f16* wp_c1  = ws + o; o += (size_t)432  * 512;
    f16* wp_out = ws + o; o += (size_t)216  * 512;
    const size_t ABUF = (size_t)32 * 32 * 32 * 128;
    f16* y_buf  = ws + o; o += ABUF;
    f16* t_buf  = ws + o; o += ABUF;
    f16* cx     = ws + o; o += ABUF;
    f16* hx_act = ws + o; o += (size_t)32 * 32 * 32 * 64;

    size_t offs[4];
    offs[0] = 0;
    offs[1] = offs[0] + (size_t)32 * 64 * 64 * 64;
    offs[2] = offs[1] + (size_t)32 * 32 * 32 * 32;
    offs[3] = offs[2] + (size_t)32 * 16 * 16 * 16;

    const dim3 blk(256);

    pack_all<<<dim3(1704), dim3(64), 0, stream>>>(
        w_h, w_c0, w_r0, w_r1, w_c1, w_out,
        wp_h, wp_c0, wp_r0, wp_r1, wp_c1, wp_out);

    // hx0 = 0.5 * conv_out(x) @64^3: tile 16x4x4 (256 px), NG4 NT2 -> grid 1024
    conv_k3<64, 16, 4, 4, 4, 2, 32, true><<<dim3(1024), blk, 0, stream>>>(
        x, wp_out, nullptr, nullptr, out + offs[0], 0, 0.5f);

    // ---- level 0: 64 -> 32 ----
    conv_k2<32, 16, 2, 1, 4, 2, true, 64, false><<<dim3(1024), blk, 0, stream>>>(
        x, wp_c0, y_buf, nullptr, 1.0f);
    conv_k3<32, 16, 4, 2, 2, 2, 64, false><<<dim3(256), blk, 0, stream>>>(
        y_buf, wp_r0, nullptr, t_buf, nullptr, 1, 1.0f);
    conv_k3<32, 16, 4, 2, 2, 2, 64, false><<<dim3(256), blk, 0, stream>>>(
        t_buf, wp_r1, y_buf, y_buf, nullptr, 0, 1.0f);
    conv_k3<32, 16, 4, 2, 2, 2, 64, false><<<dim3(256), blk, 0, stream>>>(
        y_buf, wp_c1, nullptr, cx, nullptr, 0, 1.0f);
    conv_k2<32, 16, 2, 1, 4, 1, true, 32, true><<<dim3(1024), blk, 0, stream>>>(
        out + offs[0], wp_h, nullptr, cx, 2.0f);
    conv_k3<32, 16, 4, 2, 4, 1, 32, false><<<dim3(256), blk, 0, stream>>>(
        cx, wp_out, nullptr, hx_act, out + offs[1], 0, 0.5f);

    // ---- level 1: 32 -> 16 ----
    conv_k2<16, 16, 2, 1, 4, 2, false, 64, false><<<dim3(128), blk, 0, stream>>>(
        cx, wp_c0, y_buf, nullptr, 1.0f);
    conv_k3<16, 16, 4, 2, 2, 2, 64, false><<<dim3(32), blk, 0, stream>>>(
        y_buf, wp_r0, nullptr, t_buf, nullptr, 1, 1.0f);
    conv_k3<16, 16, 4, 2, 2, 2, 64, false><<<dim3(32), blk, 0, stream>>>(
        t_buf, wp_r1, y_buf, y_buf, nullptr, 0, 1.0f);
    conv_k3<16, 16, 4, 2, 2, 2, 64, false><<<dim3(32), blk, 0, stream>>>(
        y_buf, wp_c1, nullptr, cx, nullptr, 0, 1.0f);
    conv_k2<16, 16, 2, 1, 4, 1, false, 32, true><<<dim3(128), blk, 0, stream>>>(
        hx_act, wp_h, nullptr, cx, 1.0f);
    conv_k3<16, 16, 4, 2, 4, 1, 32, false><<<dim3(32), blk, 0, stream>>>(
        cx, wp_out, nullptr, hx_act, out + offs[2], 0, 0.5f);

    // ---- level 2: 16 -> 8 ----
    conv_k2<8, 8, 4, 1, 4, 2, false, 64, false><<<dim3(16), blk, 0, stream>>>(
        cx, wp_c0, y_buf, nullptr, 1.0f);
    conv_k3<8, 8, 4, 4, 2, 2, 64, false><<<dim3(4), blk, 0, stream>>>(
        y_buf, wp_r0, nullptr, t_buf, nullptr, 1, 1.0f);
    conv_k3<8, 8, 4, 4, 2, 2, 64, false><<<dim3(4), blk, 0, stream>>>(
        t_buf, wp_r1, y_buf, y_buf, nullptr, 0, 1.0f);
    conv_k3<8, 8, 4, 4, 2, 2, 64, false><<<dim3(4), blk, 0, stream>>>(
        y_buf, wp_c1, nullptr, cx, nullptr, 0, 1.0f);
    conv_k2<8, 8, 4, 1, 4, 1, false, 32, true><<<dim3(16), blk, 0, stream>>>(
        hx_act, wp_h, nullptr, cx, 1.0f);
    conv_k3<8, 8, 4, 4, 4, 1, 32, false><<<dim3(4), blk, 0, stream>>>(
        cx, wp_out, nullptr, nullptr, out + offs[3], 0, 0.5f);
}